// Round 9
// baseline (113.307 us; speedup 1.0000x reference)
//
#include <hip/hip_runtime.h>
#include <math.h>

#define PMAX 22
#define HID 64
#define OUTD 128
#define SETS_PER_WAVE 16
#define WAVES_PER_BLOCK 4

typedef __attribute__((ext_vector_type(8))) short short8;
typedef __attribute__((ext_vector_type(4))) float float4v;
typedef _Float16 fh2 __attribute__((ext_vector_type(2)));

__device__ __forceinline__ int rl_i(int v, int l) {
    return __builtin_amdgcn_readlane(v, l);
}
// pack two fp32 -> f16x2 bits (v_cvt_pkrtz_f16_f32)
__device__ __forceinline__ int pk2(float x, float y) {
    auto v = __builtin_amdgcn_cvt_pkrtz(x, y);
    union { decltype(v) h; int i; } c;
    c.h = v;
    return c.i;
}
// f16x2 dot-product accumulate: c += a.x*b.x + a.y*b.y (v_dot2_f32_f16)
__device__ __forceinline__ float fdot2i(int a, int b, float c) {
    union { int i; fh2 h; } ua, ub;
    ua.i = a;
    ub.i = b;
#if defined(__has_builtin) && __has_builtin(__builtin_amdgcn_fdot2)
    return __builtin_amdgcn_fdot2(ua.h, ub.h, c, false);
#else
    return fmaf((float)ua.h.x, (float)ub.h.x, fmaf((float)ua.h.y, (float)ub.h.y, c));
#endif
}
// fp32 -> bf16 bits, round-to-nearest-even
__device__ __forceinline__ unsigned bf16_bits(float x) {
    unsigned u = __float_as_uint(x);
    return (u + 0x7FFFu + ((u >> 16) & 1u)) >> 16;
}
// Wave-internal LDS sync (per-wave hb slice only).
__device__ __forceinline__ void wave_lds_sync() {
    asm volatile("s_waitcnt lgkmcnt(0)" ::: "memory");
    __builtin_amdgcn_wave_barrier();
}
// Fast atan2: |err| ~1e-4 rad. Degree-7 odd minimax on [0,1].
__device__ __forceinline__ float fast_atan2(float y, float x) {
    float ax = fabsf(x), ay = fabsf(y);
    float mn = fminf(ax, ay), mx = fmaxf(ax, ay);
    float a = mn * __builtin_amdgcn_rcpf(fmaxf(mx, 1e-30f));
    float s = a * a;
    float r = a * fmaf(s, fmaf(s, fmaf(s, -0.0851330f, 0.1801410f), -0.3302995f), 0.9998660f);
    if (ay > ax) r = 1.57079637f - r;
    if (x < 0.0f) r = 3.14159274f - r;
    return copysignf(r, y);
}

// 4 blocks/CU co-resident: grid 1024, LDS 25.6 KB, VGPR capped at 128.
__global__ __launch_bounds__(256, 4) void set_encoder_kernel(
    const float* __restrict__ player_locs,  // [B,22,2]
    const float* __restrict__ actor_locs,   // [B,2]
    const float* __restrict__ flags,        // [B,22,2]
    const int*   __restrict__ mask,         // [B,22]
    const float* __restrict__ W1,           // [6,64]
    const float* __restrict__ b1,           // [64]
    const float* __restrict__ W2,           // [64,128]
    const float* __restrict__ b2,           // [128]
    float* __restrict__ out)                // [B,128]
{
    // B-fragments of W2, packed bf16 pairs (one ds_read_b128 per lane/frag).
    __shared__ __align__(16) unsigned w2f[16 * 256];                        // 16 KB
    // h-bar bf16, [wave][set][hid]; 72-short row => A-frag = aligned b128.
    __shared__ __align__(16) unsigned short hb[WAVES_PER_BLOCK][SETS_PER_WAVE][72];

    const int tid  = threadIdx.x;
    const int lane = tid & 63;
    const int wave = tid >> 6;

    const int wave_id = blockIdx.x * WAVES_PER_BLOCK + wave;
    const int set0    = wave_id * SETS_PER_WAVE;

    // --- W2 -> LDS B-fragments (block-cooperative, one-time) ---
    {
        const int pr = tid >> 3;   // k-pair 0..31 (rows 2pr, 2pr+1)
        const int nt = tid & 7;    // n-tile 0..7
        const float* rA = W2 + (size_t)(2 * pr) * OUTD + 16 * nt;
        const float* rB = rA + OUTD;
        float ra[16], rb[16];
#pragma unroll
        for (int i = 0; i < 4; ++i) {
            *(float4*)&ra[4 * i] = ((const float4*)rA)[i];
            *(float4*)&rb[4 * i] = ((const float4*)rB)[i];
        }
        const int kt = pr >> 4;
        const int kk = (2 * pr) & 31;
        const int Q  = kk >> 3;
        const int j2 = (kk >> 1) & 3;
        const int base = ((kt * 8 + nt) * 4 + Q) * 64 + j2;
#pragma unroll
        for (int c = 0; c < 16; ++c)
            w2f[base + 4 * c] = bf16_bits(ra[c]) | (bf16_bits(rb[c]) << 16);
    }

    // --- per-lane W1 column + bias, packed to f16x2 (lane = hidden unit) ---
    const int w01 = pk2(W1[0 * HID + lane], W1[1 * HID + lane]);
    const int w23 = pk2(W1[2 * HID + lane], W1[3 * HID + lane]);
    const int w45 = pk2(W1[4 * HID + lane], W1[5 * HID + lane]);
    const float b1l = b1[lane];

    __syncthreads();  // w2f visible to all waves (only block barrier)

    // --- phase 0: features for 16 sets (2 per iteration) into f16x2 regs ---
    int fh[8][3];
    unsigned long long bm[8];
#pragma unroll
    for (int g = 0; g < 8; ++g) {
        const int lidx = lane < 2 * PMAX ? lane : 2 * PMAX - 1;  // clamp
        const int grow = (set0 + 2 * g) * PMAX + lidx;
        float2 pl = ((const float2*)player_locs)[grow];
        float2 fl = ((const float2*)flags)[grow];
        int    m  = mask[grow];
        const int sl = 2 * g + (lidx >= PMAX ? 1 : 0);
        float2 ac = ((const float2*)actor_locs)[set0 + sl];
        float dx = pl.x - ac.x;
        float dy = pl.y - ac.y;
        float dist = __builtin_amdgcn_sqrtf(fmaf(dx, dx, dy * dy));
        float ang  = fast_atan2(dy, dx);
        fh[g][0] = pk2(dx, dy);
        fh[g][1] = pk2(dist, ang);
        fh[g][2] = pk2(fl.x, fl.y);
        bm[g] = __ballot((lane < 2 * PMAX) && (m != 0));
    }

    // --- phase 1: layer1 + masked pool; lane = hidden unit; SGPR bitmask
    //     skip-loop; per player: 3 readlane + 3 v_dot2_f32_f16 + max + add ---
    unsigned nonempty = 0;
#pragma unroll
    for (int s = 0; s < SETS_PER_WAVE; ++s) {
        const int g    = s >> 1;
        const int base = (s & 1) * PMAX;
        unsigned bits = (unsigned)(bm[g] >> base) & 0x3FFFFFu;
        const int cnt = __builtin_popcount(bits);
        if (bits) nonempty |= (1u << s);
        float acc = 0.0f;
        unsigned bb = bits;
        while (bb) {
            const int p = __builtin_ctz(bb);
            bb &= bb - 1;
            const int src = base + p;
            const int u0 = rl_i(fh[g][0], src);
            const int u1 = rl_i(fh[g][1], src);
            const int u2 = rl_i(fh[g][2], src);
            float t = fdot2i(u0, w01, b1l);
            t = fdot2i(u1, w23, t);
            t = fdot2i(u2, w45, t);
            acc += fmaxf(t, 0.0f);
        }
        const float hbar = acc * (1.0f / fmaxf((float)cnt, 1.0f));
        hb[wave][s][lane] = (unsigned short)bf16_bits(hbar);
    }
    wave_lds_sync();

    // --- phase 2: out[16 sets x 128] = hbar @ W2 via MFMA, full M tile.
    // A-frag (m89): lane l holds A[m=l&15][k=(l>>4)*8+j]; m = set, k = hid.
    const int Q   = lane >> 4;
    const int c15 = lane & 15;
    short8 afrag[2];
#pragma unroll
    for (int kt = 0; kt < 2; ++kt) {
        union { uint4 u4; short8 s8; } cv;
        cv.u4 = *(const uint4*)&hb[wave][c15][kt * 32 + Q * 8];  // aligned b128
        afrag[kt] = cv.s8;
    }

    float4v acc[8];
#pragma unroll
    for (int nt = 0; nt < 8; ++nt) {
        union { uint4 u4; short8 s8; } f0, f1;
        f0.u4 = *(const uint4*)&w2f[(0 * 8 + nt) * 256 + 4 * lane];
        f1.u4 = *(const uint4*)&w2f[(1 * 8 + nt) * 256 + 4 * lane];
        float4v z = {0.0f, 0.0f, 0.0f, 0.0f};
        acc[nt] = __builtin_amdgcn_mfma_f32_16x16x32_bf16(afrag[0], f0.s8, z, 0, 0, 0);
        acc[nt] = __builtin_amdgcn_mfma_f32_16x16x32_bf16(afrag[1], f1.s8, acc[nt], 0, 0, 0);
    }

    // --- epilogue: + b2 * [cnt>0]; C layout row=4Q+r (=set), col=c15; all lanes
    float b2v[8];
#pragma unroll
    for (int nt = 0; nt < 8; ++nt) b2v[nt] = b2[16 * nt + c15];

#pragma unroll
    for (int nt = 0; nt < 8; ++nt) {
#pragma unroll
        for (int r = 0; r < 4; ++r) {
            const int s = 4 * Q + r;
            const float f = (float)((nonempty >> s) & 1u);
            out[(size_t)(set0 + s) * OUTD + 16 * nt + c15] = acc[nt][r] + f * b2v[nt];
        }
    }
}

extern "C" void kernel_launch(void* const* d_in, const int* in_sizes, int n_in,
                              void* d_out, int out_size, void* d_ws, size_t ws_size,
                              hipStream_t stream) {
    const float* player_locs = (const float*)d_in[0];
    const float* actor_locs  = (const float*)d_in[1];
    const float* flags       = (const float*)d_in[2];
    const int*   mask        = (const int*)d_in[3];
    const float* W1          = (const float*)d_in[4];
    const float* b1          = (const float*)d_in[5];
    const float* W2          = (const float*)d_in[6];
    const float* b2          = (const float*)d_in[7];
    float*       out         = (float*)d_out;

    const int B = in_sizes[0] / (PMAX * 2);  // 65536
    const int sets_per_block = WAVES_PER_BLOCK * SETS_PER_WAVE;  // 64
    const int grid = (B + sets_per_block - 1) / sets_per_block;  // 1024

    hipLaunchKernelGGL(set_encoder_kernel, dim3(grid), dim3(256), 0, stream,
                       player_locs, actor_locs, flags, mask, W1, b1, W2, b2, out);
}

// Round 10
// 113.127 us; speedup vs baseline: 1.0016x; 1.0016x over previous
//
#include <hip/hip_runtime.h>
#include <math.h>

#define PMAX 22
#define HID 64
#define OUTD 128
#define SETS_PER_WAVE 16
#define WAVES_PER_BLOCK 4

typedef __attribute__((ext_vector_type(4))) float float4v;
typedef _Float16 fh2 __attribute__((ext_vector_type(2)));
typedef _Float16 half8 __attribute__((ext_vector_type(8)));

__device__ __forceinline__ int rl_i(int v, int l) {
    return __builtin_amdgcn_readlane(v, l);
}
// pack two fp32 -> f16x2 bits (v_cvt_pkrtz_f16_f32)
__device__ __forceinline__ int pk2(float x, float y) {
    auto v = __builtin_amdgcn_cvt_pkrtz(x, y);
    union { decltype(v) h; int i; } c;
    c.h = v;
    return c.i;
}
// fp32 -> f16 bits (low half of pkrtz)
__device__ __forceinline__ unsigned short f16b(float x) {
    return (unsigned short)(pk2(x, x) & 0xFFFF);
}
// f16x2 dot-product accumulate: c += a.x*b.x + a.y*b.y (v_dot2_f32_f16)
__device__ __forceinline__ float fdot2i(int a, int b, float c) {
    union { int i; fh2 h; } ua, ub;
    ua.i = a;
    ub.i = b;
#if defined(__has_builtin) && __has_builtin(__builtin_amdgcn_fdot2)
    return __builtin_amdgcn_fdot2(ua.h, ub.h, c, false);
#else
    return fmaf((float)ua.h.x, (float)ub.h.x, fmaf((float)ua.h.y, (float)ub.h.y, c));
#endif
}
// Wave-internal LDS sync (per-wave hb slice only).
__device__ __forceinline__ void wave_lds_sync() {
    asm volatile("s_waitcnt lgkmcnt(0)" ::: "memory");
    __builtin_amdgcn_wave_barrier();
}
// Fast atan2: |err| ~1e-4 rad. Degree-7 odd minimax on [0,1].
__device__ __forceinline__ float fast_atan2(float y, float x) {
    float ax = fabsf(x), ay = fabsf(y);
    float mn = fminf(ax, ay), mx = fmaxf(ax, ay);
    float a = mn * __builtin_amdgcn_rcpf(fmaxf(mx, 1e-30f));
    float s = a * a;
    float r = a * fmaf(s, fmaf(s, fmaf(s, -0.0851330f, 0.1801410f), -0.3302995f), 0.9998660f);
    if (ay > ax) r = 1.57079637f - r;
    if (x < 0.0f) r = 3.14159274f - r;
    return copysignf(r, y);
}

// 4 blocks/CU co-resident: grid 1024, LDS ~20.5 KB, VGPR capped at 128.
__global__ __launch_bounds__(256, 4) void set_encoder_kernel(
    const float* __restrict__ player_locs,  // [B,22,2]
    const float* __restrict__ actor_locs,   // [B,2]
    const float* __restrict__ flags,        // [B,22,2]
    const int*   __restrict__ mask,         // [B,22]
    const float* __restrict__ W1,           // [6,64]
    const float* __restrict__ b1,           // [64]
    const float* __restrict__ W2,           // [64,128]
    const float* __restrict__ b2,           // [128]
    float* __restrict__ out)                // [B,128]
{
    // B-fragments of W2 as f16 pairs (one ds_read_b128 per lane/frag).
    __shared__ __align__(16) unsigned w2f[16 * 256];                        // 16 KB
    // h-bar f16, [wave][set][hid]; 72-short row (144B = 9*16) keeps b128 aligned.
    __shared__ __align__(16) unsigned short hb[WAVES_PER_BLOCK][SETS_PER_WAVE][72];

    const int tid  = threadIdx.x;
    const int lane = tid & 63;
    const int wave = tid >> 6;

    const int wave_id = blockIdx.x * WAVES_PER_BLOCK + wave;
    const int set0    = wave_id * SETS_PER_WAVE;

    // --- W2 -> LDS B-fragments, f16 (block-cooperative, one-time) ---
    {
        const int pr = tid >> 3;   // k-pair 0..31 (rows 2pr, 2pr+1)
        const int nt = tid & 7;    // n-tile 0..7
        const float* rA = W2 + (size_t)(2 * pr) * OUTD + 16 * nt;
        const float* rB = rA + OUTD;
        float ra[16], rb[16];
#pragma unroll
        for (int i = 0; i < 4; ++i) {
            *(float4*)&ra[4 * i] = ((const float4*)rA)[i];
            *(float4*)&rb[4 * i] = ((const float4*)rB)[i];
        }
        const int kt = pr >> 4;
        const int kk = (2 * pr) & 31;
        const int Q  = kk >> 3;
        const int j2 = (kk >> 1) & 3;
        const int base = ((kt * 8 + nt) * 4 + Q) * 64 + j2;
#pragma unroll
        for (int c = 0; c < 16; ++c)
            w2f[base + 4 * c] = pk2(ra[c], rb[c]);  // (k even, k odd) f16 pair
    }

    // --- per-lane W1 column + bias, packed f16x2 (lane = hidden unit) ---
    const int w01 = pk2(W1[0 * HID + lane], W1[1 * HID + lane]);
    const int w23 = pk2(W1[2 * HID + lane], W1[3 * HID + lane]);
    const int w45 = pk2(W1[4 * HID + lane], W1[5 * HID + lane]);
    const float b1l = b1[lane];

    __syncthreads();  // w2f visible to all waves (only block barrier)

    // --- phase 0: features for 16 sets (2 per iter, lanes 0..43) into f16x2
    //     regs; single base pointers + compile-time offsets (g*44 rows).
    int fh[8][3];
    unsigned long long bm[8];
    {
        const int lidx = lane < 2 * PMAX ? lane : 2 * PMAX - 1;  // clamp
        const size_t r0 = (size_t)set0 * PMAX + lidx;
        const float2* plb = (const float2*)player_locs + r0;
        const float2* flb = (const float2*)flags + r0;
        const int*    mkb = mask + r0;
        const float2* acb = (const float2*)actor_locs + set0 + (lidx >= PMAX ? 1 : 0);
#pragma unroll
        for (int g = 0; g < 8; ++g) {
            float2 pl = plb[g * 2 * PMAX];
            float2 fl = flb[g * 2 * PMAX];
            int    m  = mkb[g * 2 * PMAX];
            float2 ac = acb[2 * g];
            float dx = pl.x - ac.x;
            float dy = pl.y - ac.y;
            float dist = __builtin_amdgcn_sqrtf(fmaf(dx, dx, dy * dy));
            float ang  = fast_atan2(dy, dx);
            fh[g][0] = pk2(dx, dy);
            fh[g][1] = pk2(dist, ang);
            fh[g][2] = pk2(fl.x, fl.y);
            bm[g] = __ballot((lane < 2 * PMAX) && (m != 0));
        }
    }

    // --- phase 1: layer1 + masked pool; lane = hidden unit; SGPR bitmask
    //     skip-loop; per player: 3 readlane + 3 v_dot2_f32_f16 + max + add ---
    unsigned nonempty = 0;
#pragma unroll
    for (int s = 0; s < SETS_PER_WAVE; ++s) {
        const int g    = s >> 1;
        const int base = (s & 1) * PMAX;
        unsigned bits = (unsigned)(bm[g] >> base) & 0x3FFFFFu;
        const int cnt = __builtin_popcount(bits);
        if (bits) nonempty |= (1u << s);
        float acc = 0.0f;
        unsigned bb = bits;
        while (bb) {
            const int p = __builtin_ctz(bb);
            bb &= bb - 1;
            const int src = base + p;
            const int u0 = rl_i(fh[g][0], src);
            const int u1 = rl_i(fh[g][1], src);
            const int u2 = rl_i(fh[g][2], src);
            float t = fdot2i(u0, w01, b1l);
            t = fdot2i(u1, w23, t);
            t = fdot2i(u2, w45, t);
            acc += fmaxf(t, 0.0f);
        }
        const float hbar = acc * (1.0f / fmaxf((float)cnt, 1.0f));
        hb[wave][s][lane] = f16b(hbar);
    }
    wave_lds_sync();

    // --- phase 2: out[16 sets x 128] = hbar @ W2 via f16 MFMA, full M tile.
    // A-frag: lane l holds A[m=l&15][k=(l>>4)*8+j]; m = set, k = hid.
    const int Q   = lane >> 4;
    const int c15 = lane & 15;
    half8 afrag[2];
#pragma unroll
    for (int kt = 0; kt < 2; ++kt) {
        union { uint4 u4; half8 h8; } cv;
        cv.u4 = *(const uint4*)&hb[wave][c15][kt * 32 + Q * 8];  // aligned b128
        afrag[kt] = cv.h8;
    }

    float4v acc[8];
#pragma unroll
    for (int nt = 0; nt < 8; ++nt) {
        union { uint4 u4; half8 h8; } f0, f1;
        f0.u4 = *(const uint4*)&w2f[(0 * 8 + nt) * 256 + 4 * lane];
        f1.u4 = *(const uint4*)&w2f[(1 * 8 + nt) * 256 + 4 * lane];
        float4v z = {0.0f, 0.0f, 0.0f, 0.0f};
        acc[nt] = __builtin_amdgcn_mfma_f32_16x16x32_f16(afrag[0], f0.h8, z, 0, 0, 0);
        acc[nt] = __builtin_amdgcn_mfma_f32_16x16x32_f16(afrag[1], f1.h8, acc[nt], 0, 0, 0);
    }

    // --- epilogue: + b2 * [cnt>0]; C layout row=4Q+r (=set), col=c15.
    // One store base + compile-time offsets; [cnt>0] factors hoisted.
    float fs[4];
#pragma unroll
    for (int r = 0; r < 4; ++r) fs[r] = (float)((nonempty >> (4 * Q + r)) & 1u);

    const float* b2b = b2 + c15;
    float b2v[8];
#pragma unroll
    for (int nt = 0; nt < 8; ++nt) b2v[nt] = b2b[16 * nt];

    float* obase = out + (size_t)(set0 + 4 * Q) * OUTD + c15;
#pragma unroll
    for (int nt = 0; nt < 8; ++nt) {
#pragma unroll
        for (int r = 0; r < 4; ++r)
            obase[r * OUTD + nt * 16] = fmaf(fs[r], b2v[nt], acc[nt][r]);
    }
}

extern "C" void kernel_launch(void* const* d_in, const int* in_sizes, int n_in,
                              void* d_out, int out_size, void* d_ws, size_t ws_size,
                              hipStream_t stream) {
    const float* player_locs = (const float*)d_in[0];
    const float* actor_locs  = (const float*)d_in[1];
    const float* flags       = (const float*)d_in[2];
    const int*   mask        = (const int*)d_in[3];
    const float* W1          = (const float*)d_in[4];
    const float* b1          = (const float*)d_in[5];
    const float* W2          = (const float*)d_in[6];
    const float* b2          = (const float*)d_in[7];
    float*       out         = (float*)d_out;

    const int B = in_sizes[0] / (PMAX * 2);  // 65536
    const int sets_per_block = WAVES_PER_BLOCK * SETS_PER_WAVE;  // 64
    const int grid = (B + sets_per_block - 1) / sets_per_block;  // 1024

    hipLaunchKernelGGL(set_encoder_kernel, dim3(grid), dim3(256), 0, stream,
                       player_locs, actor_locs, flags, mask, W1, b1, W2, b2, out);
}

// Round 11
// 110.762 us; speedup vs baseline: 1.0230x; 1.0213x over previous
//
#include <hip/hip_runtime.h>
#include <math.h>

#define PMAX 22
#define HID 64
#define OUTD 128
#define SETS_PER_WAVE 8
#define WAVES_PER_BLOCK 4

typedef __attribute__((ext_vector_type(4))) float float4v;
typedef _Float16 fh2 __attribute__((ext_vector_type(2)));
typedef _Float16 half8 __attribute__((ext_vector_type(8)));

__device__ __forceinline__ int rl_i(int v, int l) {
    return __builtin_amdgcn_readlane(v, l);
}
// pack two fp32 -> f16x2 bits (v_cvt_pkrtz_f16_f32)
__device__ __forceinline__ int pk2(float x, float y) {
    auto v = __builtin_amdgcn_cvt_pkrtz(x, y);
    union { decltype(v) h; int i; } c;
    c.h = v;
    return c.i;
}
// fp32 -> f16 bits (low half of pkrtz)
__device__ __forceinline__ unsigned short f16b(float x) {
    return (unsigned short)(pk2(x, x) & 0xFFFF);
}
// f16x2 dot-product accumulate: c += a.x*b.x + a.y*b.y (v_dot2_f32_f16)
__device__ __forceinline__ float fdot2i(int a, int b, float c) {
    union { int i; fh2 h; } ua, ub;
    ua.i = a;
    ub.i = b;
#if defined(__has_builtin) && __has_builtin(__builtin_amdgcn_fdot2)
    return __builtin_amdgcn_fdot2(ua.h, ub.h, c, false);
#else
    return fmaf((float)ua.h.x, (float)ub.h.x, fmaf((float)ua.h.y, (float)ub.h.y, c));
#endif
}
// Wave-internal LDS sync (per-wave hb slice only).
__device__ __forceinline__ void wave_lds_sync() {
    asm volatile("s_waitcnt lgkmcnt(0)" ::: "memory");
    __builtin_amdgcn_wave_barrier();
}
// Fast atan2: |err| ~1e-4 rad. Degree-7 odd minimax on [0,1].
__device__ __forceinline__ float fast_atan2(float y, float x) {
    float ax = fabsf(x), ay = fabsf(y);
    float mn = fminf(ax, ay), mx = fmaxf(ax, ay);
    float a = mn * __builtin_amdgcn_rcpf(fmaxf(mx, 1e-30f));
    float s = a * a;
    float r = a * fmaf(s, fmaf(s, fmaf(s, -0.0851330f, 0.1801410f), -0.3302995f), 0.9998660f);
    if (ay > ax) r = 1.57079637f - r;
    if (x < 0.0f) r = 3.14159274f - r;
    return copysignf(r, y);
}

__global__ __launch_bounds__(256) void set_encoder_kernel(
    const float* __restrict__ player_locs,  // [B,22,2]
    const float* __restrict__ actor_locs,   // [B,2]
    const float* __restrict__ flags,        // [B,22,2]
    const int*   __restrict__ mask,         // [B,22]
    const float* __restrict__ W1,           // [6,64]
    const float* __restrict__ b1,           // [64]
    const float* __restrict__ W2,           // [64,128]
    const float* __restrict__ b2,           // [128]
    float* __restrict__ out)                // [B,128]
{
    // B-fragments of W2 as f16 pairs (one ds_read_b128 per lane/frag).
    __shared__ __align__(16) unsigned w2f[16 * 256];                        // 16 KB
    // h-bar f16, [wave][set][hid]; 72-short row (144B) keeps b128 aligned.
    __shared__ __align__(16) unsigned short hb[WAVES_PER_BLOCK][SETS_PER_WAVE][72];

    const int tid  = threadIdx.x;
    const int lane = tid & 63;
    const int wave = tid >> 6;

    const int wave_id = blockIdx.x * WAVES_PER_BLOCK + wave;
    const int set0    = wave_id * SETS_PER_WAVE;

    // --- W2 -> LDS B-fragments, f16 (block-cooperative, one-time) ---
    {
        const int pr = tid >> 3;   // k-pair 0..31 (rows 2pr, 2pr+1)
        const int nt = tid & 7;    // n-tile 0..7
        const float* rA = W2 + (size_t)(2 * pr) * OUTD + 16 * nt;
        const float* rB = rA + OUTD;
        float ra[16], rb[16];
#pragma unroll
        for (int i = 0; i < 4; ++i) {
            *(float4*)&ra[4 * i] = ((const float4*)rA)[i];
            *(float4*)&rb[4 * i] = ((const float4*)rB)[i];
        }
        const int kt = pr >> 4;
        const int kk = (2 * pr) & 31;
        const int Q  = kk >> 3;
        const int j2 = (kk >> 1) & 3;
        const int base = ((kt * 8 + nt) * 4 + Q) * 64 + j2;
#pragma unroll
        for (int c = 0; c < 16; ++c)
            w2f[base + 4 * c] = pk2(ra[c], rb[c]);  // (k even, k odd) f16 pair
    }

    // --- per-lane W1 column + bias, packed f16x2 (lane = hidden unit) ---
    const int w01 = pk2(W1[0 * HID + lane], W1[1 * HID + lane]);
    const int w23 = pk2(W1[2 * HID + lane], W1[3 * HID + lane]);
    const int w45 = pk2(W1[4 * HID + lane], W1[5 * HID + lane]);
    const float b1l = b1[lane];

    __syncthreads();  // w2f visible to all waves (only block barrier)

    // --- phase 0: features for 8 sets (2 per iter, lanes 0..43) into f16x2 ---
    int fh[4][3];
    unsigned long long bm[4];
    {
        const int lidx = lane < 2 * PMAX ? lane : 2 * PMAX - 1;  // clamp
        const size_t r0 = (size_t)set0 * PMAX + lidx;
        const float2* plb = (const float2*)player_locs + r0;
        const float2* flb = (const float2*)flags + r0;
        const int*    mkb = mask + r0;
        const float2* acb = (const float2*)actor_locs + set0 + (lidx >= PMAX ? 1 : 0);
#pragma unroll
        for (int g = 0; g < 4; ++g) {
            float2 pl = plb[g * 2 * PMAX];
            float2 fl = flb[g * 2 * PMAX];
            int    m  = mkb[g * 2 * PMAX];
            float2 ac = acb[2 * g];
            float dx = pl.x - ac.x;
            float dy = pl.y - ac.y;
            float dist = __builtin_amdgcn_sqrtf(fmaf(dx, dx, dy * dy));
            float ang  = fast_atan2(dy, dx);
            fh[g][0] = pk2(dx, dy);
            fh[g][1] = pk2(dist, ang);
            fh[g][2] = pk2(fl.x, fl.y);
            bm[g] = __ballot((lane < 2 * PMAX) && (m != 0));
        }
    }

    // --- phase 1: layer1 + masked pool; lane = hidden unit; SGPR bitmask
    //     skip-loop, TWO players per iteration (independent fdot2 chains) ---
    unsigned nonempty = 0;
#pragma unroll
    for (int s = 0; s < SETS_PER_WAVE; ++s) {
        const int g    = s >> 1;
        const int base = (s & 1) * PMAX;
        unsigned bits = (unsigned)(bm[g] >> base) & 0x3FFFFFu;
        const int cnt = __builtin_popcount(bits);
        if (bits) nonempty |= (1u << s);
        float acc = 0.0f;
        unsigned bb = bits;
        const int npair = cnt >> 1;
        for (int i = 0; i < npair; ++i) {
            const int p0 = __builtin_ctz(bb); bb &= bb - 1;
            const int p1 = __builtin_ctz(bb); bb &= bb - 1;
            const int s0 = base + p0, s1 = base + p1;
            const int a0 = rl_i(fh[g][0], s0), b0 = rl_i(fh[g][0], s1);
            const int a1 = rl_i(fh[g][1], s0), b1v = rl_i(fh[g][1], s1);
            const int a2 = rl_i(fh[g][2], s0), b2v = rl_i(fh[g][2], s1);
            float t0 = fdot2i(a0, w01, b1l);
            float t1 = fdot2i(b0, w01, b1l);
            t0 = fdot2i(a1, w23, t0);
            t1 = fdot2i(b1v, w23, t1);
            t0 = fdot2i(a2, w45, t0);
            t1 = fdot2i(b2v, w45, t1);
            acc += fmaxf(t0, 0.0f);
            acc += fmaxf(t1, 0.0f);
        }
        if (cnt & 1) {
            const int p = __builtin_ctz(bb);
            const int src = base + p;
            float t = fdot2i(rl_i(fh[g][0], src), w01, b1l);
            t = fdot2i(rl_i(fh[g][1], src), w23, t);
            t = fdot2i(rl_i(fh[g][2], src), w45, t);
            acc += fmaxf(t, 0.0f);
        }
        const float hbar = acc * (1.0f / fmaxf((float)cnt, 1.0f));
        hb[wave][s][lane] = f16b(hbar);
    }
    wave_lds_sync();

    // --- phase 2: out[8 sets x 128] = hbar @ W2 via f16 MFMA.
    // A-frag: lane l holds A[m=l&15][k=(l>>4)*8+j]; rows 8..15 dup (unstored).
    const int Q   = lane >> 4;
    const int c15 = lane & 15;
    const int sA  = lane & 7;
    half8 afrag[2];
#pragma unroll
    for (int kt = 0; kt < 2; ++kt) {
        union { uint4 u4; half8 h8; } cv;
        cv.u4 = *(const uint4*)&hb[wave][sA][kt * 32 + Q * 8];  // aligned b128
        afrag[kt] = cv.h8;
    }

    float4v acc[8];
#pragma unroll
    for (int nt = 0; nt < 8; ++nt) {
        union { uint4 u4; half8 h8; } f0, f1;
        f0.u4 = *(const uint4*)&w2f[(0 * 8 + nt) * 256 + 4 * lane];
        f1.u4 = *(const uint4*)&w2f[(1 * 8 + nt) * 256 + 4 * lane];
        float4v z = {0.0f, 0.0f, 0.0f, 0.0f};
        acc[nt] = __builtin_amdgcn_mfma_f32_16x16x32_f16(afrag[0], f0.h8, z, 0, 0, 0);
        acc[nt] = __builtin_amdgcn_mfma_f32_16x16x32_f16(afrag[1], f1.h8, acc[nt], 0, 0, 0);
    }

    // --- epilogue: + b2 * [cnt>0]; C row=4Q+r (=set for Q<2), col=c15 ---
    if (Q < 2) {
        float fs[4];
#pragma unroll
        for (int r = 0; r < 4; ++r) fs[r] = (float)((nonempty >> (4 * Q + r)) & 1u);

        const float* b2b = b2 + c15;
        float b2v[8];
#pragma unroll
        for (int nt = 0; nt < 8; ++nt) b2v[nt] = b2b[16 * nt];

        float* obase = out + (size_t)(set0 + 4 * Q) * OUTD + c15;
#pragma unroll
        for (int nt = 0; nt < 8; ++nt) {
#pragma unroll
            for (int r = 0; r < 4; ++r)
                obase[r * OUTD + nt * 16] = fmaf(fs[r], b2v[nt], acc[nt][r]);
        }
    }
}

extern "C" void kernel_launch(void* const* d_in, const int* in_sizes, int n_in,
                              void* d_out, int out_size, void* d_ws, size_t ws_size,
                              hipStream_t stream) {
    const float* player_locs = (const float*)d_in[0];
    const float* actor_locs  = (const float*)d_in[1];
    const float* flags       = (const float*)d_in[2];
    const int*   mask        = (const int*)d_in[3];
    const float* W1          = (const float*)d_in[4];
    const float* b1          = (const float*)d_in[5];
    const float* W2          = (const float*)d_in[6];
    const float* b2          = (const float*)d_in[7];
    float*       out         = (float*)d_out;

    const int B = in_sizes[0] / (PMAX * 2);  // 65536
    const int sets_per_block = WAVES_PER_BLOCK * SETS_PER_WAVE;  // 32
    const int grid = (B + sets_per_block - 1) / sets_per_block;  // 2048

    hipLaunchKernelGGL(set_encoder_kernel, dim3(grid), dim3(256), 0, stream,
                       player_locs, actor_locs, flags, mask, W1, b1, W2, b2, out);
}

// Round 12
// 110.368 us; speedup vs baseline: 1.0266x; 1.0036x over previous
//
#include <hip/hip_runtime.h>
#include <math.h>

#define PMAX 22
#define HID 64
#define OUTD 128
#define SETS_PER_WAVE 8
#define WAVES_PER_BLOCK 4

typedef __attribute__((ext_vector_type(4))) float float4v;
typedef _Float16 fh2 __attribute__((ext_vector_type(2)));
typedef _Float16 half8 __attribute__((ext_vector_type(8)));

__device__ __forceinline__ int rl_i(int v, int l) {
    return __builtin_amdgcn_readlane(v, l);
}
// pack two fp32 -> f16x2 bits (v_cvt_pkrtz_f16_f32)
__device__ __forceinline__ int pk2(float x, float y) {
    auto v = __builtin_amdgcn_cvt_pkrtz(x, y);
    union { decltype(v) h; int i; } c;
    c.h = v;
    return c.i;
}
// fp32 -> f16 bits (low half of pkrtz)
__device__ __forceinline__ unsigned short f16b(float x) {
    return (unsigned short)(pk2(x, x) & 0xFFFF);
}
// f16x2 dot-product accumulate: c += a.x*b.x + a.y*b.y (v_dot2_f32_f16)
__device__ __forceinline__ float fdot2i(int a, int b, float c) {
    union { int i; fh2 h; } ua, ub;
    ua.i = a;
    ub.i = b;
#if defined(__has_builtin) && __has_builtin(__builtin_amdgcn_fdot2)
    return __builtin_amdgcn_fdot2(ua.h, ub.h, c, false);
#else
    return fmaf((float)ua.h.x, (float)ub.h.x, fmaf((float)ua.h.y, (float)ub.h.y, c));
#endif
}
// Wave-internal LDS sync (per-wave hb slice only).
__device__ __forceinline__ void wave_lds_sync() {
    asm volatile("s_waitcnt lgkmcnt(0)" ::: "memory");
    __builtin_amdgcn_wave_barrier();
}
// Fast atan2: |err| ~1e-4 rad. Degree-7 odd minimax on [0,1].
__device__ __forceinline__ float fast_atan2(float y, float x) {
    float ax = fabsf(x), ay = fabsf(y);
    float mn = fminf(ax, ay), mx = fmaxf(ax, ay);
    float a = mn * __builtin_amdgcn_rcpf(fmaxf(mx, 1e-30f));
    float s = a * a;
    float r = a * fmaf(s, fmaf(s, fmaf(s, -0.0851330f, 0.1801410f), -0.3302995f), 0.9998660f);
    if (ay > ax) r = 1.57079637f - r;
    if (x < 0.0f) r = 3.14159274f - r;
    return copysignf(r, y);
}

__global__ __launch_bounds__(256) void set_encoder_kernel(
    const float* __restrict__ player_locs,  // [B,22,2]
    const float* __restrict__ actor_locs,   // [B,2]
    const float* __restrict__ flags,        // [B,22,2]
    const int*   __restrict__ mask,         // [B,22]
    const float* __restrict__ W1,           // [6,64]
    const float* __restrict__ b1,           // [64]
    const float* __restrict__ W2,           // [64,128]
    const float* __restrict__ b2,           // [128]
    float* __restrict__ out)                // [B,128]
{
    // B-fragments of W2 as f16 pairs (one ds_read_b128 per lane/frag).
    __shared__ __align__(16) unsigned w2f[16 * 256];                        // 16 KB
    // h-bar f16, [wave][set][hid]; 72-short row (144B) keeps b128 aligned.
    __shared__ __align__(16) unsigned short hb[WAVES_PER_BLOCK][SETS_PER_WAVE][72];

    const int tid  = threadIdx.x;
    const int lane = tid & 63;
    const int wave = tid >> 6;

    const int wave_id = blockIdx.x * WAVES_PER_BLOCK + wave;
    const int set0    = wave_id * SETS_PER_WAVE;

    // --- W2 -> LDS B-fragments, f16 (block-cooperative, one-time) ---
    {
        const int pr = tid >> 3;   // k-pair 0..31 (rows 2pr, 2pr+1)
        const int nt = tid & 7;    // n-tile 0..7
        const float* rA = W2 + (size_t)(2 * pr) * OUTD + 16 * nt;
        const float* rB = rA + OUTD;
        float ra[16], rb[16];
#pragma unroll
        for (int i = 0; i < 4; ++i) {
            *(float4*)&ra[4 * i] = ((const float4*)rA)[i];
            *(float4*)&rb[4 * i] = ((const float4*)rB)[i];
        }
        const int kt = pr >> 4;
        const int kk = (2 * pr) & 31;
        const int Q  = kk >> 3;
        const int j2 = (kk >> 1) & 3;
        const int base = ((kt * 8 + nt) * 4 + Q) * 64 + j2;
#pragma unroll
        for (int c = 0; c < 16; ++c)
            w2f[base + 4 * c] = pk2(ra[c], rb[c]);  // (k even, k odd) f16 pair
    }

    // --- per-lane W1 column + bias, packed f16x2 (lane = hidden unit) ---
    const int w01 = pk2(W1[0 * HID + lane], W1[1 * HID + lane]);
    const int w23 = pk2(W1[2 * HID + lane], W1[3 * HID + lane]);
    const int w45 = pk2(W1[4 * HID + lane], W1[5 * HID + lane]);
    const float b1l = b1[lane];

    __syncthreads();  // w2f visible to all waves (only block barrier)

    // --- phase 0: features for 8 sets (2 per iter, lanes 0..43) into f16x2;
    //     validity bitmap moved to SGPRs via readfirstlane (wave-uniform). ---
    int fh[4][3];
    unsigned long long wbm[4];  // scalar 44-bit window per set-pair
    {
        const int lidx = lane < 2 * PMAX ? lane : 2 * PMAX - 1;  // clamp
        const size_t r0 = (size_t)set0 * PMAX + lidx;
        const float2* plb = (const float2*)player_locs + r0;
        const float2* flb = (const float2*)flags + r0;
        const int*    mkb = mask + r0;
        const float2* acb = (const float2*)actor_locs + set0 + (lidx >= PMAX ? 1 : 0);
#pragma unroll
        for (int g = 0; g < 4; ++g) {
            float2 pl = plb[g * 2 * PMAX];
            float2 fl = flb[g * 2 * PMAX];
            int    m  = mkb[g * 2 * PMAX];
            float2 ac = acb[2 * g];
            float dx = pl.x - ac.x;
            float dy = pl.y - ac.y;
            float dist = __builtin_amdgcn_sqrtf(fmaf(dx, dx, dy * dy));
            float ang  = fast_atan2(dy, dx);
            fh[g][0] = pk2(dx, dy);
            fh[g][1] = pk2(dist, ang);
            fh[g][2] = pk2(fl.x, fl.y);
            unsigned long long bl = __ballot((lane < 2 * PMAX) && (m != 0));
            const unsigned lo = __builtin_amdgcn_readfirstlane((unsigned)bl);
            const unsigned hi = __builtin_amdgcn_readfirstlane((unsigned)(bl >> 32));
            wbm[g] = ((unsigned long long)hi << 32) | lo;  // uniform (SGPR pair)
        }
    }

    // --- phase 1: layer1 + masked pool; lane = hidden unit.
    //     Fully unrolled p-loop; per player a UNIFORM scalar branch
    //     (s_bitcmp+s_cbranch) guards an 8-VALU body whose readlane index
    //     is a compile-time immediate. No VGPR loop state, no ctz chain. ---
    unsigned nonempty = 0;
#pragma unroll
    for (int s = 0; s < SETS_PER_WAVE; ++s) {
        const int g    = s >> 1;
        const int base = (s & 1) * PMAX;
        const unsigned bits = (unsigned)(wbm[g] >> base) & 0x3FFFFFu;  // uniform
        const int cnt = __builtin_popcount(bits);
        if (bits) nonempty |= (1u << s);
        float acc = 0.0f;
#pragma unroll
        for (int p = 0; p < PMAX; ++p) {
            if (bits & (1u << p)) {
                float t = fdot2i(rl_i(fh[g][0], base + p), w01, b1l);
                t = fdot2i(rl_i(fh[g][1], base + p), w23, t);
                t = fdot2i(rl_i(fh[g][2], base + p), w45, t);
                acc += fmaxf(t, 0.0f);
            }
        }
        const float hbar = acc * (1.0f / fmaxf((float)cnt, 1.0f));
        hb[wave][s][lane] = f16b(hbar);
    }
    wave_lds_sync();

    // --- phase 2: out[8 sets x 128] = hbar @ W2 via f16 MFMA.
    // A-frag: lane l holds A[m=l&15][k=(l>>4)*8+j]; rows 8..15 dup (unstored).
    const int Q   = lane >> 4;
    const int c15 = lane & 15;
    const int sA  = lane & 7;
    half8 afrag[2];
#pragma unroll
    for (int kt = 0; kt < 2; ++kt) {
        union { uint4 u4; half8 h8; } cv;
        cv.u4 = *(const uint4*)&hb[wave][sA][kt * 32 + Q * 8];  // aligned b128
        afrag[kt] = cv.h8;
    }

    float4v acc[8];
#pragma unroll
    for (int nt = 0; nt < 8; ++nt) {
        union { uint4 u4; half8 h8; } f0, f1;
        f0.u4 = *(const uint4*)&w2f[(0 * 8 + nt) * 256 + 4 * lane];
        f1.u4 = *(const uint4*)&w2f[(1 * 8 + nt) * 256 + 4 * lane];
        float4v z = {0.0f, 0.0f, 0.0f, 0.0f};
        acc[nt] = __builtin_amdgcn_mfma_f32_16x16x32_f16(afrag[0], f0.h8, z, 0, 0, 0);
        acc[nt] = __builtin_amdgcn_mfma_f32_16x16x32_f16(afrag[1], f1.h8, acc[nt], 0, 0, 0);
    }

    // --- epilogue: + b2 * [cnt>0]; C row=4Q+r (=set for Q<2), col=c15 ---
    if (Q < 2) {
        float fs[4];
#pragma unroll
        for (int r = 0; r < 4; ++r) fs[r] = (float)((nonempty >> (4 * Q + r)) & 1u);

        const float* b2b = b2 + c15;
        float b2v[8];
#pragma unroll
        for (int nt = 0; nt < 8; ++nt) b2v[nt] = b2b[16 * nt];

        float* obase = out + (size_t)(set0 + 4 * Q) * OUTD + c15;
#pragma unroll
        for (int nt = 0; nt < 8; ++nt) {
#pragma unroll
            for (int r = 0; r < 4; ++r)
                obase[r * OUTD + nt * 16] = fmaf(fs[r], b2v[nt], acc[nt][r]);
        }
    }
}

extern "C" void kernel_launch(void* const* d_in, const int* in_sizes, int n_in,
                              void* d_out, int out_size, void* d_ws, size_t ws_size,
                              hipStream_t stream) {
    const float* player_locs = (const float*)d_in[0];
    const float* actor_locs  = (const float*)d_in[1];
    const float* flags       = (const float*)d_in[2];
    const int*   mask        = (const int*)d_in[3];
    const float* W1          = (const float*)d_in[4];
    const float* b1          = (const float*)d_in[5];
    const float* W2          = (const float*)d_in[6];
    const float* b2          = (const float*)d_in[7];
    float*       out         = (float*)d_out;

    const int B = in_sizes[0] / (PMAX * 2);  // 65536
    const int sets_per_block = WAVES_PER_BLOCK * SETS_PER_WAVE;  // 32
    const int grid = (B + sets_per_block - 1) / sets_per_block;  // 2048

    hipLaunchKernelGGL(set_encoder_kernel, dim3(grid), dim3(256), 0, stream,
                       player_locs, actor_locs, flags, mask, W1, b1, W2, b2, out);
}